// Round 1
// baseline (248.765 us; speedup 1.0000x reference)
//
#include <hip/hip_runtime.h>

#define EPS 1e-8f

constexpr int NROWS  = 1024;  // rows of x and of y
constexpr int K      = 256;   // feature dim
constexpr int TILE   = 32;    // 32x32 output tile per 64-thread (1-wave) block
constexpr int KC     = 64;    // k-chunk staged in LDS
constexpr int PITCH  = KC + 4; // 68 floats: 272B rows (16B aligned), spreads banks
constexpr int NCHUNK = K / KC; // 4

// Single fused kernel.
// - 1 wave per block: no __syncthreads in the main loop (DS ops are in-order
//   within a wave, so single-buffer LDS staging is race-free).
// - Register double-buffer: next chunk's 16x global_load_dwordx4 issued BEFORE
//   the ~2048-cycle compute phase; ds_write after -> HBM/L2 latency fully hidden.
// - Row sums (needed for den = Sx + Sy - num + EPS) are accumulated from the
//   prefetch registers (granule-partial per lane), shuffle-reduced over the 16
//   granule lanes at the end: ~3% VALU overhead, kills the separate rowsum
//   kernel + its launch gap.
__global__ __launch_bounds__(64) void ruzicka_fused(const float* __restrict__ x,
                                                    const float* __restrict__ y,
                                                    float* __restrict__ out) {
    __shared__ __align__(16) float buf[2 * TILE][PITCH]; // rows 0..31: x tile, 32..63: y tile
    __shared__ __align__(16) float ssum[2 * TILE];       // full-K row sums of the tile rows

    const int tid  = threadIdx.x;  // 0..63
    const int tx   = tid & 7;      // output col group (y rows)
    const int ty   = tid >> 3;     // output row group (x rows)
    const int gl   = tid & 15;     // staging granule within a row (16B)
    const int rsub = tid >> 4;     // staging row sub-index (0..3)
    const int rowBase = blockIdx.y * TILE;
    const int colBase = blockIdx.x * TILE;

    // staging: instr i covers rows rsub+4i (i<8: x rows, i>=8: y rows), 16 lanes
    // x 16B = 256B contiguous per row -> fully coalesced.
    const float* xp = x + (size_t)(rowBase + rsub) * K + gl * 4;
    const float* yp = y + (size_t)(colBase + rsub) * K + gl * 4;

    float num[4][4];
    #pragma unroll
    for (int r = 0; r < 4; ++r)
        #pragma unroll
        for (int c = 0; c < 4; ++c) num[r][c] = 0.0f;

    float racc[16];                // granule-partial row sums: racc[i] ~ buf row rsub+4i
    #pragma unroll
    for (int i = 0; i < 16; ++i) racc[i] = 0.0f;

    float4 h[16];

    // ---- prologue: stage chunk 0 ----
    #pragma unroll
    for (int i = 0; i < 8; ++i) h[i]     = *(const float4*)(xp + (size_t)(4 * i) * K);
    #pragma unroll
    for (int i = 0; i < 8; ++i) h[8 + i] = *(const float4*)(yp + (size_t)(4 * i) * K);
    #pragma unroll
    for (int i = 0; i < 16; ++i) {
        racc[i] += (h[i].x + h[i].y) + (h[i].z + h[i].w);
        *(float4*)&buf[rsub + 4 * i][gl * 4] = h[i];   // buf row rsub+4i == x row / 32+y row
    }

    #pragma unroll 1
    for (int t = 0; t < NCHUNK; ++t) {
        // issue next chunk's loads first -> latency hides under compute
        if (t + 1 < NCHUNK) {
            const int kc = (t + 1) * KC;
            #pragma unroll
            for (int i = 0; i < 8; ++i) h[i]     = *(const float4*)(xp + (size_t)(4 * i) * K + kc);
            #pragma unroll
            for (int i = 0; i < 8; ++i) h[8 + i] = *(const float4*)(yp + (size_t)(4 * i) * K + kc);
        }

        // compute current chunk from LDS (each granule read exactly once)
        #pragma unroll
        for (int kk = 0; kk < KC; kk += 4) {
            float4 a[4], b[4];
            #pragma unroll
            for (int r = 0; r < 4; ++r) a[r] = *(const float4*)&buf[ty * 4 + r][kk];
            #pragma unroll
            for (int c = 0; c < 4; ++c) b[c] = *(const float4*)&buf[TILE + tx * 4 + c][kk];
            #pragma unroll
            for (int r = 0; r < 4; ++r)
                #pragma unroll
                for (int c = 0; c < 4; ++c) {
                    const float m0 = fminf(a[r].x, b[c].x);
                    const float m1 = fminf(a[r].y, b[c].y);
                    const float m2 = fminf(a[r].z, b[c].z);
                    const float m3 = fminf(a[r].w, b[c].w);
                    num[r][c] += (m0 + m1) + (m2 + m3);
                }
        }

        // overwrite LDS with the prefetched chunk (reads above already issued;
        // DS is in-order within the wave)
        if (t + 1 < NCHUNK) {
            #pragma unroll
            for (int i = 0; i < 16; ++i) {
                racc[i] += (h[i].x + h[i].y) + (h[i].z + h[i].w);
                *(float4*)&buf[rsub + 4 * i][gl * 4] = h[i];
            }
        }
    }

    // ---- finish row sums: reduce over the 16 granule lanes (same rsub group) ----
    #pragma unroll
    for (int m = 1; m <= 8; m <<= 1) {
        #pragma unroll
        for (int i = 0; i < 16; ++i) racc[i] += __shfl_xor(racc[i], m, 64);
    }
    if (gl == 0) {
        #pragma unroll
        for (int i = 0; i < 16; ++i) ssum[rsub + 4 * i] = racc[i];
    }
    __syncthreads();  // 1-wave block: near-free; orders ssum for the reads below

    const float4 sxv = *(const float4*)&ssum[ty * 4];
    const float4 syv = *(const float4*)&ssum[TILE + tx * 4];
    const float sxa[4] = {sxv.x, sxv.y, sxv.z, sxv.w};
    const float sya[4] = {syv.x, syv.y, syv.z, syv.w};

    #pragma unroll
    for (int r = 0; r < 4; ++r) {
        float4 o;
        float* op = &o.x;
        #pragma unroll
        for (int c = 0; c < 4; ++c) {
            const float n = num[r][c];
            op[c] = n / (sxa[r] + sya[c] - n + EPS);  // den = Sx + Sy - num + EPS
        }
        *(float4*)&out[(size_t)(rowBase + ty * 4 + r) * NROWS + colBase + tx * 4] = o;
    }
}

extern "C" void kernel_launch(void* const* d_in, const int* in_sizes, int n_in,
                              void* d_out, int out_size, void* d_ws, size_t ws_size,
                              hipStream_t stream) {
    const float* x = (const float*)d_in[0];
    const float* y = (const float*)d_in[1];
    float* out = (float*)d_out;
    (void)d_ws; (void)ws_size;

    // 32x32 tiles -> 1024 one-wave blocks (4 blocks/CU across 256 CUs)
    ruzicka_fused<<<dim3(NROWS / TILE, NROWS / TILE), dim3(64), 0, stream>>>(x, y, out);
}

// Round 2
// 119.922 us; speedup vs baseline: 2.0744x; 2.0744x over previous
//
#include <hip/hip_runtime.h>
#include <stdint.h>

#define EPS 1e-8f

constexpr int NROWS  = 1024;  // rows of x and of y
constexpr int K      = 256;   // feature dim
constexpr int TILE   = 32;    // 32x32 output tile per 64-thread (1-wave) block
constexpr int KC     = 64;    // k-chunk staged in LDS
constexpr int NCHUNK = K / KC;

typedef __attribute__((address_space(3))) uint32_t* lds_ptr_t;
typedef const __attribute__((address_space(1))) uint32_t* glb_ptr_t;

// Single fused kernel, 1 wave per block (no __syncthreads in the hot path).
// - Staging via global_load_lds (width 16): zero VGPR cost -> no spills
//   (round-1 failure mode: h[16] float4 prefetch => 256 VGPR + 555 MB scratch).
// - global_load_lds writes LDS linearly (lane*16B), so bank-conflict avoidance
//   uses rule #21: linear LDS dest + XOR-pre-swizzled GLOBAL source + the same
//   XOR on the read side. Swizzle: float_off ^= ((row>>2)&7)<<2. A-reads (8
//   broadcast groups over ty) then hit 8 disjoint bank quads: conflict-free.
// - Row sums (den = Sx + Sy - num + EPS): global-read prologue, lane l sums
//   tile row l over full K; distributed at the end via 8 __shfl. No LDS array,
//   no second kernel, no workspace.
__global__ __launch_bounds__(64) void ruzicka_fused(const float* __restrict__ x,
                                                    const float* __restrict__ y,
                                                    float* __restrict__ out) {
    __shared__ __align__(16) float buf[64 * KC];  // rows 0..31: x tile, 32..63: y tile (swizzled)

    const int tid = threadIdx.x;   // 0..63
    const int tx  = tid & 7;       // output col group (y rows)
    const int ty  = tid >> 3;      // output row group (x rows)
    const int g   = tid & 15;      // staging granule (16B) within a row
    const int r4  = tid >> 4;      // staging row sub-index (0..3)
    const int rowBase = blockIdx.y * TILE;
    const int colBase = blockIdx.x * TILE;

    const float* xb = x + (size_t)(rowBase + r4) * K;
    const float* yb = y + (size_t)(colBase + r4) * K;

    // Stage one 64-wide k-chunk: 16 global_load_lds, each moving 4 rows x 256B
    // = 1024B linear LDS. Source granule is (g ^ i) so that the data landing at
    // linear slot (row, g) is the one the swizzled read expects.
    auto stage = [&](int kc) {
        #pragma unroll
        for (int i = 0; i < 8; ++i) {
            const float* gx = xb + (size_t)(4 * i) * K + kc + 4 * (g ^ i);
            const float* gy = yb + (size_t)(4 * i) * K + kc + 4 * (g ^ i);
            __builtin_amdgcn_global_load_lds((glb_ptr_t)gx, (lds_ptr_t)&buf[i * 256],       16, 0, 0);
            __builtin_amdgcn_global_load_lds((glb_ptr_t)gy, (lds_ptr_t)&buf[(8 + i) * 256], 16, 0, 0);
        }
    };

    stage(0);  // chunk-0 DMA latency hides under the row-sum prologue below

    // ---- prologue: full-K row sums, lane l -> tile row l ----
    const float* srow = (tid < 32) ? (x + (size_t)(rowBase + tid) * K)
                                   : (y + (size_t)(colBase + tid - 32) * K);
    float s = 0.0f;
    #pragma unroll 16
    for (int j = 0; j < K / 4; ++j) {
        const float4 v = ((const float4*)srow)[j];
        s += (v.x + v.y) + (v.z + v.w);
    }

    float num[4][4];
    #pragma unroll
    for (int r = 0; r < 4; ++r)
        #pragma unroll
        for (int c = 0; c < 4; ++c) num[r][c] = 0.0f;

    #pragma unroll 1
    for (int t = 0; t < NCHUNK; ++t) {
        if (t > 0) {
            // all ds_reads of the previous chunk retired before the DMA overwrite
            asm volatile("s_waitcnt lgkmcnt(0)" ::: "memory");
            stage(t * KC);
        }
        // DMA for this chunk landed in LDS before any ds_read of it
        asm volatile("s_waitcnt vmcnt(0)" ::: "memory");
        __builtin_amdgcn_sched_barrier(0);

        #pragma unroll
        for (int kk = 0; kk < KC; kk += 4) {
            float4 a[4], b[4];
            #pragma unroll
            for (int r = 0; r < 4; ++r)
                a[r] = *(const float4*)&buf[(ty * 4 + r) * KC + (kk ^ (ty << 2))];
            #pragma unroll
            for (int c = 0; c < 4; ++c)
                b[c] = *(const float4*)&buf[(32 + tx * 4 + c) * KC + (kk ^ (tx << 2))];
            #pragma unroll
            for (int r = 0; r < 4; ++r)
                #pragma unroll
                for (int c = 0; c < 4; ++c) {
                    const float m0 = fminf(a[r].x, b[c].x);
                    const float m1 = fminf(a[r].y, b[c].y);
                    const float m2 = fminf(a[r].z, b[c].z);
                    const float m3 = fminf(a[r].w, b[c].w);
                    num[r][c] += (m0 + m1) + (m2 + m3);
                }
        }
    }

    // ---- distribute row sums: lane (ty*4+r) holds Sx, lane (32+tx*4+c) holds Sy ----
    float sx[4], sy[4];
    #pragma unroll
    for (int r = 0; r < 4; ++r) sx[r] = __shfl(s, ty * 4 + r, 64);
    #pragma unroll
    for (int c = 0; c < 4; ++c) sy[c] = __shfl(s, 32 + tx * 4 + c, 64);

    #pragma unroll
    for (int r = 0; r < 4; ++r) {
        float4 o;
        float* op = &o.x;
        #pragma unroll
        for (int c = 0; c < 4; ++c) {
            const float n = num[r][c];
            op[c] = n / (sx[r] + sy[c] - n + EPS);  // den = Sx + Sy - num + EPS
        }
        *(float4*)&out[(size_t)(rowBase + ty * 4 + r) * NROWS + colBase + tx * 4] = o;
    }
}

extern "C" void kernel_launch(void* const* d_in, const int* in_sizes, int n_in,
                              void* d_out, int out_size, void* d_ws, size_t ws_size,
                              hipStream_t stream) {
    const float* x = (const float*)d_in[0];
    const float* y = (const float*)d_in[1];
    float* out = (float*)d_out;
    (void)d_ws; (void)ws_size;

    // 32x32 tiles -> 1024 one-wave blocks (4 blocks/CU across 256 CUs)
    ruzicka_fused<<<dim3(NROWS / TILE, NROWS / TILE), dim3(64), 0, stream>>>(x, y, out);
}

// Round 3
// 82.858 us; speedup vs baseline: 3.0023x; 1.4473x over previous
//
#include <hip/hip_runtime.h>
#include <stdint.h>

#define EPS 1e-8f

constexpr int NROWS  = 1024;  // rows of x and of y
constexpr int K      = 256;   // feature dim
constexpr int TILE   = 32;    // 32x32 output tile per 64-thread (1-wave) block
constexpr int KC     = 64;    // k-chunk staged in LDS
constexpr int NCHUNK = K / KC;

typedef __attribute__((address_space(3))) uint32_t* lds_ptr_t;
typedef const __attribute__((address_space(1))) uint32_t* glb_ptr_t;

// Fused Ruzicka kernel, 1 wave per block, no barriers in the hot path.
// Round-3 changes vs round-2:
//  - kk loop: #pragma unroll 2 (was full unroll) -> bounded ds_read live
//    ranges. Round-2 spilled (VGPR=256, 60 MB scratch writes) because the
//    scheduler hoisted 16 iterations x 32 VGPRs of load results.
//  - Double-buffered LDS + counted vmcnt(16): stage chunk t+1 while computing
//    chunk t; the 16 newest outstanding vmem ops are chunk t+1's, so
//    vmcnt(16) guarantees chunk t has landed (T4 pattern, never vmcnt(0)
//    mid-loop). DMA latency hides under ~4k cycles of compute.
// Carried forward (verified round 2: passed, bank conflicts = 0):
//  - global_load_lds width 16 staging (zero VGPR cost).
//  - Rule #21 swizzle: linear LDS dest + XOR-pre-swizzled global source
//    (granule g^i) + same XOR on reads (kk ^ (group<<2)) -> conflict-free.
//  - Fused row sums: global-read prologue (covers chunk-0 DMA latency),
//    distributed via __shfl in the epilogue. No workspace use.
__global__ __launch_bounds__(64) void ruzicka_fused(const float* __restrict__ x,
                                                    const float* __restrict__ y,
                                                    float* __restrict__ out) {
    __shared__ __align__(16) float buf[2][64 * KC];  // 2 x 16 KB k-chunk buffers

    const int tid = threadIdx.x;   // 0..63
    const int tx  = tid & 7;       // output col group (y rows)
    const int ty  = tid >> 3;      // output row group (x rows)
    const int g   = tid & 15;      // staging granule (16B) within a row
    const int r4  = tid >> 4;      // staging row sub-index (0..3)
    const int rowBase = blockIdx.y * TILE;
    const int colBase = blockIdx.x * TILE;

    const float* xb = x + (size_t)(rowBase + r4) * K;
    const float* yb = y + (size_t)(colBase + r4) * K;

    // Stage one 64-wide k-chunk into buffer b: 16 global_load_lds, each moving
    // 4 rows x 256B = 1024B linear LDS. Source granule (g ^ i) pre-applies the
    // read-side swizzle.
    auto stage = [&](int kc, int b) {
        #pragma unroll
        for (int i = 0; i < 8; ++i) {
            const float* gx = xb + (size_t)(4 * i) * K + kc + 4 * (g ^ i);
            const float* gy = yb + (size_t)(4 * i) * K + kc + 4 * (g ^ i);
            __builtin_amdgcn_global_load_lds((glb_ptr_t)gx, (lds_ptr_t)&buf[b][i * 256],       16, 0, 0);
            __builtin_amdgcn_global_load_lds((glb_ptr_t)gy, (lds_ptr_t)&buf[b][(8 + i) * 256], 16, 0, 0);
        }
    };

    stage(0, 0);  // chunk-0 DMA latency hides under the row-sum prologue

    // ---- prologue: full-K row sums, lane l -> tile row l ----
    const float* srow = (tid < 32) ? (x + (size_t)(rowBase + tid) * K)
                                   : (y + (size_t)(colBase + tid - 32) * K);
    float s = 0.0f;
    #pragma unroll 8
    for (int j = 0; j < K / 4; ++j) {
        const float4 v = ((const float4*)srow)[j];
        s += (v.x + v.y) + (v.z + v.w);
    }

    float num[4][4];
    #pragma unroll
    for (int r = 0; r < 4; ++r)
        #pragma unroll
        for (int c = 0; c < 4; ++c) num[r][c] = 0.0f;

    const int ka0 = ty << 2;
    const int kb0 = tx << 2;

    #pragma unroll
    for (int t = 0; t < NCHUNK; ++t) {
        if (t + 1 < NCHUNK) {
            // fence: previous-chunk ds_reads must not sink below this DMA
            // (it overwrites the buffer they read two iterations from now)
            __builtin_amdgcn_sched_barrier(0);
            stage((t + 1) * KC, (t + 1) & 1);
            // 16 newest outstanding = chunk t+1's; all older (chunk t) landed
            asm volatile("s_waitcnt vmcnt(16)" ::: "memory");
        } else {
            asm volatile("s_waitcnt vmcnt(0)" ::: "memory");
        }
        __builtin_amdgcn_sched_barrier(0);

        const float* bb = buf[t & 1];  // t-loop fully unrolled -> static index

        #pragma unroll 2
        for (int kk = 0; kk < KC; kk += 4) {
            const int ka = kk ^ ka0;
            const int kb = kk ^ kb0;
            float4 a[4], b4[4];
            #pragma unroll
            for (int r = 0; r < 4; ++r)
                a[r] = *(const float4*)&bb[(ty * 4 + r) * KC + ka];
            #pragma unroll
            for (int c = 0; c < 4; ++c)
                b4[c] = *(const float4*)&bb[(32 + tx * 4 + c) * KC + kb];
            #pragma unroll
            for (int r = 0; r < 4; ++r)
                #pragma unroll
                for (int c = 0; c < 4; ++c) {
                    const float m0 = fminf(a[r].x, b4[c].x);
                    const float m1 = fminf(a[r].y, b4[c].y);
                    const float m2 = fminf(a[r].z, b4[c].z);
                    const float m3 = fminf(a[r].w, b4[c].w);
                    num[r][c] += (m0 + m1) + (m2 + m3);
                }
        }
    }

    // ---- distribute row sums: lane (ty*4+r) holds Sx, lane (32+tx*4+c) holds Sy ----
    float sx[4], sy[4];
    #pragma unroll
    for (int r = 0; r < 4; ++r) sx[r] = __shfl(s, ty * 4 + r, 64);
    #pragma unroll
    for (int c = 0; c < 4; ++c) sy[c] = __shfl(s, 32 + tx * 4 + c, 64);

    #pragma unroll
    for (int r = 0; r < 4; ++r) {
        float4 o;
        float* op = &o.x;
        #pragma unroll
        for (int c = 0; c < 4; ++c) {
            const float n = num[r][c];
            op[c] = n / (sx[r] + sy[c] - n + EPS);  // den = Sx + Sy - num + EPS
        }
        *(float4*)&out[(size_t)(rowBase + ty * 4 + r) * NROWS + colBase + tx * 4] = o;
    }
}

extern "C" void kernel_launch(void* const* d_in, const int* in_sizes, int n_in,
                              void* d_out, int out_size, void* d_ws, size_t ws_size,
                              hipStream_t stream) {
    const float* x = (const float*)d_in[0];
    const float* y = (const float*)d_in[1];
    float* out = (float*)d_out;
    (void)d_ws; (void)ws_size;

    // 32x32 tiles -> 1024 one-wave blocks (4 blocks/CU across 256 CUs)
    ruzicka_fused<<<dim3(NROWS / TILE, NROWS / TILE), dim3(64), 0, stream>>>(x, y, out);
}